// Round 6
// baseline (423.040 us; speedup 1.0000x reference)
//
#include <hip/hip_runtime.h>

#define N_GRAPHS    8
#define EDGES_PER_G 2048
#define NN          8192
#define EE          16384
#define IN_DIM      10
#define EDGE_DIM    9
#define HID         64
#define OUT_DIM     3
#define TT          5
#define EPSN        1e-6f

typedef float f32x4 __attribute__((ext_vector_type(4)));
typedef short bf16x8s __attribute__((ext_vector_type(8)));

union BF8 { __bf16 h[8]; bf16x8s v; };

// async global->LDS, 16B per lane. lds ptr must be wave-uniform; data for lane l
// lands at lds + l*16.
__device__ inline void gld16(const void* g, void* l) {
  __builtin_amdgcn_global_load_lds(
      (const __attribute__((address_space(1))) void*)g,
      (__attribute__((address_space(3))) void*)l, 16, 0, 0);
}

// ================= edge MLP, 16 edges per 256-thr block, LDS-staged weights ======
// h2T[c*EE+e] = relu(relu(norm(ear[e]) @ w1 + b1) @ w2 + b2)[c]
__device__ inline void edgemlp16(int e0, int tid,
    const float* __restrict__ ear, const float* __restrict__ meanb,
    const float* __restrict__ invstd,
    const float* __restrict__ w1, const float* __restrict__ b1,
    const float* __restrict__ w2, const float* __restrict__ b2,
    float* __restrict__ h2T,
    float* w1s, float* w2s, float* bb, float (*sh)[HID], float (*st)[HID]) {
  // ---- stage weights to LDS ----
  for (int i = tid; i < EDGE_DIM * HID; i += 256) w1s[i] = w1[i];
  {
    const float4* gw = (const float4*)w2;
    float4* lw = (float4*)w2s;
#pragma unroll
    for (int r = 0; r < 4; ++r) lw[r * 256 + tid] = gw[r * 256 + tid];
  }
  if (tid < HID) bb[tid] = b1[tid];
  else if (tid < 2 * HID) bb[tid] = b2[tid - HID];
  __syncthreads();

  int g = tid >> 6, lane = tid & 63;
  int c = tid >> 2, eo = tid & 3;
#pragma unroll
  for (int r = 0; r < 4; ++r) {
    int e0r = e0 + r * 4;
    int e = e0r + g;
    int gg = e >> 11;
    const float* er = ear + (size_t)e * EDGE_DIM;
    const float* mb = meanb + gg * EDGE_DIM;
    const float* is = invstd + gg * EDGE_DIM;
    float xn[EDGE_DIM];
#pragma unroll
    for (int d = 0; d < EDGE_DIM; ++d) xn[d] = (er[d] - mb[d]) * is[d];
    float a = bb[lane];
#pragma unroll
    for (int d = 0; d < EDGE_DIM; ++d) a += xn[d] * w1s[d * HID + lane];
    sh[g][lane] = fmaxf(a, 0.f);
    __syncthreads();
    float o = bb[HID + lane];
#pragma unroll
    for (int h = 0; h < HID; ++h) o += sh[g][h] * w2s[h * HID + lane];
    st[g][lane] = fmaxf(o, 0.f);
    __syncthreads();
    h2T[(size_t)c * EE + e0r + eo] = st[eo][c];
    __syncthreads();
  }
}

// ===== preamble: lift | bprep(LDS permute) | deg | stats | zero-aggr =============
__global__ __launch_bounds__(256) void k_pre(
    const float* __restrict__ x,
    const float* __restrict__ lw1, const float* __restrict__ lb1,
    const float* __restrict__ lw2, const float* __restrict__ lb2,
    float* __restrict__ v,
    const float* __restrict__ kw3, const float* __restrict__ kb3,
    unsigned short* __restrict__ Bbf,
    const int* __restrict__ dst, float* __restrict__ degf,
    const float* __restrict__ ear, float* __restrict__ meanb,
    float* __restrict__ invstd, float* __restrict__ aggr) {
  __shared__ float sh[4][HID];
  __shared__ __align__(16) unsigned short permbuf[4096];
  int b = blockIdx.x;
  int g = threadIdx.x >> 6, lane = threadIdx.x & 63;
  if (b < NN / 4) {
    // ---- lift MLP ----
    int n = b * 4 + g;
    const float* xr = x + n * IN_DIM;
    float a = lb1[lane];
#pragma unroll
    for (int d = 0; d < IN_DIM; ++d) a += xr[d] * lw1[d * HID + lane];
    sh[g][lane] = fmaxf(a, 0.f);
    __syncthreads();
    float o = lb2[lane];
#pragma unroll
    for (int h = 0; h < HID; ++h) o += sh[g][h] * lw2[h * HID + lane];
    v[n * HID + lane] = o;
  } else if (b < NN / 4 + TT * 65) {
    // ---- bprep: one (t,c) slab per block. Dense float4 reads of kw3 row,
    //      bf16-convert, permute to fragment-major via LDS, dense 16B writes.
    //      out index xx: sn=s*4+nt (<<9) | q(<<7) | n15(<<3) | jj
    //      in  index x_in = (nt*16+n15)*64 + s*32 + q*8 + jj
    int slab = b - NN / 4;
    int t = slab / 65;
    int c = slab - t * 65;
    const float* srcrow = (c < 64) ? kw3 + (size_t)(t * 64 + c) * 4096
                                   : kb3 + (size_t)t * 4096;
#pragma unroll
    for (int r = 0; r < 4; ++r) {
      int i4 = r * 256 + threadIdx.x;
      float4 val = ((const float4*)srcrow)[i4];
      float vv[4] = {val.x, val.y, val.z, val.w};
#pragma unroll
      for (int kk = 0; kk < 4; ++kk) {
        int x_in = i4 * 4 + kk;
        int jj = x_in & 7;
        int qq = (x_in >> 3) & 3;
        int ss = (x_in >> 5) & 1;
        int nn = (x_in >> 6) & 15;
        int nt = (x_in >> 10) & 3;
        int xx = ((ss * 4 + nt) << 9) | (qq << 7) | (nn << 3) | jj;
        union { __bf16 h; unsigned short s16; } u;
        u.h = (__bf16)vv[kk];
        permbuf[xx] = u.s16;
      }
    }
    __syncthreads();
    unsigned short* outp = Bbf + (size_t)slab * 4096;
#pragma unroll
    for (int r = 0; r < 2; ++r) {
      int off = r * 2048 + threadIdx.x * 8;
      *(bf16x8s*)(outp + off) = *(const bf16x8s*)(permbuf + off);
    }
  } else if (b < NN / 4 + TT * 65 + EE / 256) {
    // ---- deg histogram ----
    int e = (b - (NN / 4 + TT * 65)) * 256 + threadIdx.x;
    atomicAdd(&degf[dst[e]], 1.f);
  } else if (b < NN / 4 + TT * 65 + EE / 256 + N_GRAPHS) {
    // ---- per-graph edge_attr stats ----
    int gg = b - (NN / 4 + TT * 65 + EE / 256);
    float* ssum = &sh[0][0];
    float* ssq  = &sh[1][0];
    if (threadIdx.x < EDGE_DIM) { ssum[threadIdx.x] = 0.f; ssq[threadIdx.x] = 0.f; }
    __syncthreads();
    float ls[EDGE_DIM], lq[EDGE_DIM];
#pragma unroll
    for (int d = 0; d < EDGE_DIM; ++d) { ls[d] = 0.f; lq[d] = 0.f; }
    for (int e = threadIdx.x; e < EDGES_PER_G; e += blockDim.x) {
      const float* row = ear + (size_t)(gg * EDGES_PER_G + e) * EDGE_DIM;
#pragma unroll
      for (int d = 0; d < EDGE_DIM; ++d) { float xv = row[d]; ls[d] += xv; lq[d] += xv * xv; }
    }
#pragma unroll
    for (int d = 0; d < EDGE_DIM; ++d) { atomicAdd(&ssum[d], ls[d]); atomicAdd(&ssq[d], lq[d]); }
    __syncthreads();
    if (threadIdx.x < EDGE_DIM) {
      float m  = ssum[threadIdx.x] * (1.0f / EDGES_PER_G);
      float mq = ssq[threadIdx.x] * (1.0f / EDGES_PER_G);
      float var = fmaxf(mq - m * m, 0.f);
      meanb[gg * EDGE_DIM + threadIdx.x]  = m;
      invstd[gg * EDGE_DIM + threadIdx.x] = 1.f / (sqrtf(var) + EPSN);
    }
  } else {
    // ---- zero aggr (float4, 512 blocks) ----
    int idx = (b - (NN / 4 + TT * 65 + EE / 256 + N_GRAPHS)) * 256 + threadIdx.x;
    ((float4*)aggr)[idx] = make_float4(0.f, 0.f, 0.f, 0.f);
  }
}

// ---------------- standalone edge MLP (layer 0), EE/16 blocks ----------------
__global__ __launch_bounds__(256) void k_em(const float* __restrict__ ear,
    const float* __restrict__ meanb, const float* __restrict__ invstd,
    const float* __restrict__ w1, const float* __restrict__ b1,
    const float* __restrict__ w2, const float* __restrict__ b2,
    float* __restrict__ h2T) {
  __shared__ float w1s[EDGE_DIM * HID];
  __shared__ float w2s[HID * HID];
  __shared__ float bb[2 * HID];
  __shared__ float sh[4][HID];
  __shared__ float st[4][HID];
  edgemlp16(blockIdx.x * 16, threadIdx.x, ear, meanb, invstd,
            w1, b1, w2, b2, h2T, w1s, w2s, bb, sh, st);
}

// ======== msg GEMM: Msg[E,64] = A[E,4160] @ B[4160,64], scatter by dst ===========
// A[e, c*64+j] = h2[e,c] * v[src[e], j]  (row c==64: h2==1 -> bias b3)
// B staged global->LDS via global_load_lds (fragment-major layout = linear),
// double-buffered 2-c-row slabs, consumed with ds_read_b128.
// Grid: 256 edge-groups (64 edges) x 4 kchunks = 1024 blocks of 128 thr (2 waves).
#define MSG_SLAB 2
__global__ __launch_bounds__(128) void k_msg(const float* __restrict__ v,
    const float* __restrict__ h2T, const unsigned short* __restrict__ Bt,
    const int* __restrict__ src, const int* __restrict__ dst,
    float* __restrict__ aggr) {
  __shared__ __align__(16) short sB[2][MSG_SLAB * 4096];   // 2 x 16KB
  int kchunk = blockIdx.x & 3;
  int eg     = blockIdx.x >> 2;
  int w    = threadIdx.x >> 6;            // wave 0/1
  int lane = threadIdx.x & 63;
  int n15  = lane & 15;
  int q    = lane >> 4;
  int ebase = eg * 64 + w * 32;

  float4 vs[2][2][2];   // [m-tile][k-step s][half]: v[src[e]][s*32 + q*8 .. +8]
#pragma unroll
  for (int mt = 0; mt < 2; ++mt) {
    int e = ebase + mt * 16 + n15;
    const float4* vr = (const float4*)(v + (size_t)src[e] * HID);
    int f0 = q * 2;
    vs[mt][0][0] = vr[f0];     vs[mt][0][1] = vr[f0 + 1];
    vs[mt][1][0] = vr[8 + f0]; vs[mt][1][1] = vr[8 + f0 + 1];
  }

  f32x4 acc[2][4];
#pragma unroll
  for (int mt = 0; mt < 2; ++mt)
#pragma unroll
    for (int nt = 0; nt < 4; ++nt) acc[mt][nt] = (f32x4)0.0f;

  int c0 = kchunk * 16;
  int nrow = (kchunk == 3) ? 17 : 16;                // +bias row c=64 on chunk 3
  int nslab = (nrow + MSG_SLAB - 1) / MSG_SLAB;

  // stage slab s into buffer b: rows c0+s*2 .. (1KB wave-chunks, split by wave)
  auto STAGE = [&](int s, int bsel) {
    int r0 = s * MSG_SLAB;
    int nr = nrow - r0; if (nr > MSG_SLAB) nr = MSG_SLAB;
    const unsigned short* gsrc = Bt + (size_t)(c0 + r0) * 4096;
    int nchunk = nr * 8;
    for (int i = w; i < nchunk; i += 2)
      gld16(gsrc + i * 512 + lane * 8, &sB[bsel][i * 512]);
  };

  auto ROW = [&](const short* Sb, int rr, float h0, float h1) {
    bf16x8s bfr[2][4];
#pragma unroll
    for (int s = 0; s < 2; ++s)
#pragma unroll
      for (int nt = 0; nt < 4; ++nt)
        bfr[s][nt] = *(const bf16x8s*)&Sb[rr * 4096 + (s * 4 + nt) * 512 + lane * 8];
    float hh[2] = {h0, h1};
    bf16x8s afr[2][2];
#pragma unroll
    for (int mt = 0; mt < 2; ++mt) {
      float hc = hh[mt];
#pragma unroll
      for (int s = 0; s < 2; ++s) {
        BF8 u;
        float4 pa = vs[mt][s][0], pb = vs[mt][s][1];
        u.h[0] = (__bf16)(hc * pa.x); u.h[1] = (__bf16)(hc * pa.y);
        u.h[2] = (__bf16)(hc * pa.z); u.h[3] = (__bf16)(hc * pa.w);
        u.h[4] = (__bf16)(hc * pb.x); u.h[5] = (__bf16)(hc * pb.y);
        u.h[6] = (__bf16)(hc * pb.z); u.h[7] = (__bf16)(hc * pb.w);
        afr[mt][s] = u.v;
      }
    }
#pragma unroll
    for (int s = 0; s < 2; ++s)
#pragma unroll
      for (int mt = 0; mt < 2; ++mt)
#pragma unroll
        for (int nt = 0; nt < 4; ++nt)
          acc[mt][nt] = __builtin_amdgcn_mfma_f32_16x16x32_bf16(
              afr[mt][s], bfr[s][nt], acc[mt][nt], 0, 0, 0);
  };

  STAGE(0, 0);
  __syncthreads();                       // drain vmcnt + barrier
  for (int s = 0; s < nslab; ++s) {
    if (s + 1 < nslab) STAGE(s + 1, (s + 1) & 1);
    int r0 = s * MSG_SLAB;
    int nr = nrow - r0; if (nr > MSG_SLAB) nr = MSG_SLAB;
    const short* Sb = sB[s & 1];
    // h2 values for this slab (global; row c==64 -> 1.0)
    int ca = c0 + r0;
    float h00, h01, h10 = 1.f, h11 = 1.f;
    if (ca < 64) {
      h00 = h2T[(size_t)ca * EE + ebase + n15];
      h01 = h2T[(size_t)ca * EE + ebase + 16 + n15];
    } else { h00 = 1.f; h01 = 1.f; }
    if (nr == 2) {
      int cb = ca + 1;
      if (cb < 64) {
        h10 = h2T[(size_t)cb * EE + ebase + n15];
        h11 = h2T[(size_t)cb * EE + ebase + 16 + n15];
      }
      ROW(Sb, 0, h00, h01);
      ROW(Sb, 1, h10, h11);
    } else {
      ROW(Sb, 0, h00, h01);
    }
    __syncthreads();                     // drains next-slab stage + buf protect
  }

  // epilogue: C/D row = q*4+r (edge), col = n15; scatter-add by dst
#pragma unroll
  for (int mt = 0; mt < 2; ++mt) {
#pragma unroll
    for (int r = 0; r < 4; ++r) {
      int e = ebase + mt * 16 + q * 4 + r;
      int d = dst[e];
      float* ag = aggr + (size_t)d * HID;
#pragma unroll
      for (int nt = 0; nt < 4; ++nt)
        atomicAdd(ag + nt * 16 + n15, acc[mt][nt][r]);
    }
  }
}

// ==== update(t), 16 nodes/block [blocks 0..511] + edge MLP t+1 [512..1535] =======
__global__ __launch_bounds__(256) void k_upd_em(
    float* __restrict__ v, const float* __restrict__ rw, const float* __restrict__ rb,
    float* __restrict__ aggr, const float* __restrict__ degf,
    const float* __restrict__ ear, const float* __restrict__ meanb,
    const float* __restrict__ invstd,
    const float* __restrict__ w1, const float* __restrict__ b1,
    const float* __restrict__ w2, const float* __restrict__ b2,
    float* __restrict__ h2T) {
  __shared__ float w1s[EDGE_DIM * HID];
  __shared__ float w2s[HID * HID];
  __shared__ float bb[2 * HID];
  __shared__ float sh[4][HID];
  __shared__ float st[4][HID];
  int tid = threadIdx.x;
  int g = tid >> 6, lane = tid & 63;
  if (blockIdx.x < NN / 16) {
    // stage rw (16KB) + rb
    {
      const float4* gw = (const float4*)rw;
      float4* lw = (float4*)w2s;
#pragma unroll
      for (int r = 0; r < 4; ++r) lw[r * 256 + tid] = gw[r * 256 + tid];
    }
    if (tid < HID) bb[tid] = rb[tid];
    __syncthreads();
    int n0 = blockIdx.x * 16;
#pragma unroll
    for (int r = 0; r < 4; ++r) {
      int n = n0 + r * 4 + g;
      int idx = n * HID + lane;
      sh[g][lane] = v[idx];
      __syncthreads();
      float inv = 1.f / fmaxf(degf[n], 1.f);
      float o = bb[lane] + aggr[idx] * inv;
      aggr[idx] = 0.f;                   // re-zero for next layer
#pragma unroll
      for (int h = 0; h < HID; ++h) o += sh[g][h] * w2s[h * HID + lane];
      v[idx] = fmaxf(o, 0.f);
      __syncthreads();
    }
  } else {
    int e0 = (blockIdx.x - NN / 16) * 16;
    edgemlp16(e0, tid, ear, meanb, invstd, w1, b1, w2, b2, h2T,
              w1s, w2s, bb, sh, st);
  }
}

// ------- final layer: update(T-1) + proj fused (per-node elementwise) ------------
__global__ __launch_bounds__(256) void k_upd_proj(
    const float* __restrict__ v, const float* __restrict__ rw,
    const float* __restrict__ rb,
    const float* __restrict__ aggr, const float* __restrict__ degf,
    const float* __restrict__ pw1, const float* __restrict__ pb1,
    const float* __restrict__ pw2, const float* __restrict__ pb2,
    float* __restrict__ out) {
  __shared__ float sh[4][HID];
  int g = threadIdx.x >> 6, lane = threadIdx.x & 63;
  int n = blockIdx.x * 4 + g;
  int idx = n * HID + lane;
  sh[g][lane] = v[idx];
  __syncthreads();
  float inv = 1.f / fmaxf(degf[n], 1.f);
  float o = rb[lane] + aggr[idx] * inv;
#pragma unroll
  for (int h = 0; h < HID; ++h) o += sh[g][h] * rw[h * HID + lane];
  float vn = fmaxf(o, 0.f);
  __syncthreads();
  sh[g][lane] = vn;
  __syncthreads();
  float a = pb1[lane];
#pragma unroll
  for (int h = 0; h < HID; ++h) a += sh[g][h] * pw1[h * HID + lane];
  float h1 = fmaxf(a, 0.f);
  __syncthreads();
  sh[g][lane] = h1;
  __syncthreads();
  if (lane < OUT_DIM) {
    float oo = pb2[lane];
#pragma unroll
    for (int h = 0; h < HID; ++h) oo += sh[g][h] * pw2[h * OUT_DIM + lane];
    out[n * OUT_DIM + lane] = oo;
  }
}

extern "C" void kernel_launch(void* const* d_in, const int* in_sizes, int n_in,
                              void* d_out, int out_size, void* d_ws, size_t ws_size,
                              hipStream_t stream) {
  const float* x        = (const float*)d_in[0];
  const float* ear      = (const float*)d_in[1];
  const float* lift_w1  = (const float*)d_in[2];
  const float* lift_b1  = (const float*)d_in[3];
  const float* lift_w2  = (const float*)d_in[4];
  const float* lift_b2  = (const float*)d_in[5];
  const float* root_w   = (const float*)d_in[6];
  const float* root_b   = (const float*)d_in[7];
  const float* kw1      = (const float*)d_in[8];
  const float* kb1      = (const float*)d_in[9];
  const float* kw2      = (const float*)d_in[10];
  const float* kb2      = (const float*)d_in[11];
  const float* kw3      = (const float*)d_in[12];
  const float* kb3      = (const float*)d_in[13];
  const float* pw1      = (const float*)d_in[14];
  const float* pb1      = (const float*)d_in[15];
  const float* pw2      = (const float*)d_in[16];
  const float* pb2      = (const float*)d_in[17];
  const int* edge_index = (const int*)d_in[18];
  const int* src = edge_index;
  const int* dst = edge_index + EE;
  float* out = (float*)d_out;

  float* ws     = (float*)d_ws;
  float* aggr   = ws;                          // NN*HID
  float* degf   = aggr + NN * HID;             // NN
  float* h2T    = degf + NN;                   // HID*EE (transposed)
  float* vbuf   = h2T + (size_t)HID * EE;      // NN*HID
  float* meanb  = vbuf + NN * HID;             // 72
  float* invstd = meanb + 72;                  // 72
  unsigned short* Bbf = (unsigned short*)(invstd + 72);  // TT*65*4096 bf16

  hipMemsetAsync(degf, 0, NN * sizeof(float), stream);
  const int PRE_BLOCKS = NN / 4 + TT * 65 + EE / 256 + N_GRAPHS + NN * HID / 1024;
  k_pre<<<PRE_BLOCKS, 256, 0, stream>>>(
      x, lift_w1, lift_b1, lift_w2, lift_b2, vbuf, kw3, kb3, Bbf,
      dst, degf, ear, meanb, invstd, aggr);
  k_em<<<EE / 16, 256, 0, stream>>>(ear, meanb, invstd,
      kw1, kb1, kw2, kb2, h2T);

  for (int t = 0; t < TT; ++t) {
    k_msg<<<1024, 128, 0, stream>>>(vbuf, h2T, Bbf + (size_t)t * 65 * 4096,
                                    src, dst, aggr);
    if (t < TT - 1) {
      int tt = t + 1;
      k_upd_em<<<NN / 16 + EE / 16, 256, 0, stream>>>(
          vbuf, root_w + (size_t)t * HID * HID, root_b + (size_t)t * HID,
          aggr, degf, ear, meanb, invstd,
          kw1 + (size_t)tt * EDGE_DIM * HID, kb1 + (size_t)tt * HID,
          kw2 + (size_t)tt * HID * HID, kb2 + (size_t)tt * HID, h2T);
    } else {
      k_upd_proj<<<NN / 4, 256, 0, stream>>>(
          vbuf, root_w + (size_t)t * HID * HID, root_b + (size_t)t * HID,
          aggr, degf, pw1, pb1, pw2, pb2, out);
    }
  }
}